// Round 1
// baseline (732.650 us; speedup 1.0000x reference)
//
#include <hip/hip_runtime.h>
#include <math.h>

#define B_SZ   16
#define C_IN   768
#define HW_SZ  4096
#define D_OUT  256
#define M_CL   32
#define INV_EPS 20.0f
#define NORM_C (-8.32554817f)   /* -log(32+4096) */

// ---------------------------------------------------------------------------
// K1: 1x1 conv as GEMM.  x[b][c][n] (n contig) * W[d][c] (c contig) -> xp[b][n][d]
// 128(n) x 128(d) block tile, BK=16, 256 threads, 8x8 micro-tile.
// ---------------------------------------------------------------------------
__global__ __launch_bounds__(256) void conv_gemm(const float* __restrict__ x,
                                                 const float* __restrict__ W,
                                                 const float* __restrict__ bias,
                                                 float* __restrict__ xp) {
    __shared__ float As[16][132];   // [k][n], pad 132 (4 mod 32, 16B aligned)
    __shared__ float Bs[16][132];   // [k][d]
    const int tid = threadIdx.x;
    const int b  = blockIdx.z;
    const int n0 = blockIdx.x * 128;
    const int d0 = blockIdx.y * 128;
    const int tx = tid & 15, ty = tid >> 4;
    const float* xb = x + (size_t)b * C_IN * HW_SZ;

    float acc[8][8];
#pragma unroll
    for (int i = 0; i < 8; ++i)
#pragma unroll
        for (int j = 0; j < 8; ++j) acc[i][j] = 0.f;

    for (int k0 = 0; k0 < C_IN; k0 += 16) {
        // stage A: 16k x 128n = 512 float4
#pragma unroll
        for (int t = 0; t < 2; ++t) {
            int f = tid + t * 256;
            int kk = f >> 5, n4 = f & 31;
            float4 av = *(const float4*)(xb + (size_t)(k0 + kk) * HW_SZ + n0 + n4 * 4);
            *(float4*)&As[kk][n4 * 4] = av;
        }
        // stage B transposed: 128d x 16k
#pragma unroll
        for (int t = 0; t < 2; ++t) {
            int f = tid + t * 256;
            int dd = f >> 2, k4 = f & 3;
            float4 bv = *(const float4*)(W + (size_t)(d0 + dd) * C_IN + k0 + k4 * 4);
            Bs[k4 * 4 + 0][dd] = bv.x;
            Bs[k4 * 4 + 1][dd] = bv.y;
            Bs[k4 * 4 + 2][dd] = bv.z;
            Bs[k4 * 4 + 3][dd] = bv.w;
        }
        __syncthreads();
#pragma unroll
        for (int kk = 0; kk < 16; ++kk) {
            float4 t0 = *(float4*)&As[kk][ty * 4];
            float4 t1 = *(float4*)&As[kk][ty * 4 + 64];
            float4 t2 = *(float4*)&Bs[kk][tx * 4];
            float4 t3 = *(float4*)&Bs[kk][tx * 4 + 64];
            float a[8] = {t0.x, t0.y, t0.z, t0.w, t1.x, t1.y, t1.z, t1.w};
            float bb[8] = {t2.x, t2.y, t2.z, t2.w, t3.x, t3.y, t3.z, t3.w};
#pragma unroll
            for (int i = 0; i < 8; ++i)
#pragma unroll
                for (int j = 0; j < 8; ++j) acc[i][j] += a[i] * bb[j];
        }
        __syncthreads();
    }
    float4 bi0 = *(const float4*)(bias + d0 + tx * 4);
    float4 bi1 = *(const float4*)(bias + d0 + tx * 4 + 64);
#pragma unroll
    for (int h = 0; h < 2; ++h)
#pragma unroll
        for (int ii = 0; ii < 4; ++ii) {
            int i = h * 4 + ii;
            int n = n0 + ty * 4 + ii + h * 64;
            float* op = xp + ((size_t)b * HW_SZ + n) * D_OUT + d0;
            float4 o0 = make_float4(acc[i][0] + bi0.x, acc[i][1] + bi0.y,
                                    acc[i][2] + bi0.z, acc[i][3] + bi0.w);
            float4 o1 = make_float4(acc[i][4] + bi1.x, acc[i][5] + bi1.y,
                                    acc[i][6] + bi1.z, acc[i][7] + bi1.w);
            *(float4*)(op + tx * 4) = o0;
            *(float4*)(op + tx * 4 + 64) = o1;
        }
}

// ---------------------------------------------------------------------------
// K2: per-row inverse L2 norm of xp rows (256 elems). One wave per row.
// ---------------------------------------------------------------------------
__global__ __launch_bounds__(256) void row_norms(const float* __restrict__ xp,
                                                 float* __restrict__ inv_norm) {
    const int tid = threadIdx.x;
    const int lane = tid & 63, wid = tid >> 6;
    const int row = blockIdx.x * 4 + wid;
    const float* r = xp + (size_t)row * D_OUT;
    float4 v = *(const float4*)(r + lane * 4);
    float s = v.x * v.x + v.y * v.y + v.z * v.z + v.w * v.w;
#pragma unroll
    for (int off = 32; off > 0; off >>= 1) s += __shfl_xor(s, off);
    if (lane == 0) inv_norm[row] = 1.0f / fmaxf(sqrtf(s), 1e-12f);
}

// ---------------------------------------------------------------------------
// K3: normalize cluster weights v[32][256] -> w_n
// ---------------------------------------------------------------------------
__global__ void w_norm(const float* __restrict__ v_in, float* __restrict__ w_n) {
    const int lane = threadIdx.x;
    const int row = blockIdx.x;
    float4 v = *(const float4*)(v_in + row * 256 + lane * 4);
    float s = v.x * v.x + v.y * v.y + v.z * v.z + v.w * v.w;
#pragma unroll
    for (int off = 32; off > 0; off >>= 1) s += __shfl_xor(s, off);
    float inv = 1.0f / fmaxf(sqrtf(s), 1e-12f);
    float4 o = make_float4(v.x * inv, v.y * inv, v.z * inv, v.w * inv);
    *(float4*)(w_n + row * 256 + lane * 4) = o;
}

// ---------------------------------------------------------------------------
// K4: Z[b][m][n] = (xf[b][n][:] . w_n[m][:]) / EPS.  Block: 128 n x 32 m.
// thread tile: 2 n x 8 m. c staged in 64-wide chunks.
// ---------------------------------------------------------------------------
__global__ __launch_bounds__(256) void scores_k(const float* __restrict__ xp,
                                                const float* __restrict__ inv_norm,
                                                const float* __restrict__ w_n,
                                                float* __restrict__ Z) {
    __shared__ float xs[128][68];
    __shared__ float wsl[32][68];
    const int tid = threadIdx.x;
    const int b = blockIdx.y, n0 = blockIdx.x * 128;
    const int ng = tid >> 2, mg = tid & 3;
    const float* xpb = xp + ((size_t)b * HW_SZ + n0) * D_OUT;
    const float* invb = inv_norm + b * HW_SZ + n0;

    float acc[2][8];
#pragma unroll
    for (int i = 0; i < 2; ++i)
#pragma unroll
        for (int j = 0; j < 8; ++j) acc[i][j] = 0.f;

    for (int c0 = 0; c0 < 256; c0 += 64) {
#pragma unroll
        for (int t = 0; t < 8; ++t) {   // 128 rows x 16 float4
            int f = tid + t * 256;
            int row = f >> 4, c4 = f & 15;
            float4 v = *(const float4*)(xpb + (size_t)row * D_OUT + c0 + c4 * 4);
            float s = invb[row];
            v.x *= s; v.y *= s; v.z *= s; v.w *= s;
            *(float4*)&xs[row][c4 * 4] = v;
        }
#pragma unroll
        for (int t = 0; t < 2; ++t) {   // 32 rows x 16 float4
            int f = tid + t * 256;
            int row = f >> 4, c4 = f & 15;
            *(float4*)&wsl[row][c4 * 4] =
                *(const float4*)(w_n + row * 256 + c0 + c4 * 4);
        }
        __syncthreads();
#pragma unroll
        for (int c4 = 0; c4 < 16; ++c4) {
            float4 xv[2], wv[8];
#pragma unroll
            for (int i = 0; i < 2; ++i) xv[i] = *(float4*)&xs[ng + i * 64][c4 * 4];
#pragma unroll
            for (int j = 0; j < 8; ++j) wv[j] = *(float4*)&wsl[mg + j * 4][c4 * 4];
#pragma unroll
            for (int i = 0; i < 2; ++i)
#pragma unroll
                for (int j = 0; j < 8; ++j)
                    acc[i][j] += xv[i].x * wv[j].x + xv[i].y * wv[j].y +
                                 xv[i].z * wv[j].z + xv[i].w * wv[j].w;
        }
        __syncthreads();
    }
#pragma unroll
    for (int i = 0; i < 2; ++i)
#pragma unroll
        for (int j = 0; j < 8; ++j) {
            int n = n0 + ng + i * 64;
            int m = mg + j * 4;
            Z[((size_t)b * M_CL + m) * HW_SZ + n] = acc[i][j] * INV_EPS;
        }
}

// ---------------------------------------------------------------------------
// K5: Sinkhorn, one block (1024 thr) per batch. u-phase: 32 lanes per m row,
// online LSE, intra-32-lane shuffle reduce only. v-phase: 4 columns/thread.
// ---------------------------------------------------------------------------
__global__ __launch_bounds__(1024) void sinkhorn_k(const float* __restrict__ Z,
                                                   float* __restrict__ u_g,
                                                   float* __restrict__ v_g) {
    __shared__ float u_s[32];
    __shared__ float v_s[4096];
    const int tid = threadIdx.x;
    const int b = blockIdx.x;
    const float* Zb = Z + (size_t)b * M_CL * HW_SZ;
#pragma unroll
    for (int j = 0; j < 4; ++j) v_s[tid + j * 1024] = 0.f;
    __syncthreads();

    for (int it = 0; it < 3; ++it) {
        {   // u update: u[m] = NORM_C - lse_n(Z[m][n] + v[n])
            const int m = tid >> 5, l = tid & 31;
            const float* zr = Zb + (size_t)m * HW_SZ;
            float mx = -INFINITY, s = 0.f;
            for (int j = 0; j < 128; ++j) {
                int n = l + j * 32;
                float val = zr[n] + v_s[n];
                float nm = fmaxf(mx, val);
                s = s * __expf(mx - nm) + __expf(val - nm);
                mx = nm;
            }
#pragma unroll
            for (int off = 16; off > 0; off >>= 1) {
                float omx = __shfl_xor(mx, off);
                float os  = __shfl_xor(s, off);
                float nm = fmaxf(mx, omx);
                s = s * __expf(mx - nm) + os * __expf(omx - nm);
                mx = nm;
            }
            if (l == 0) u_s[m] = NORM_C - (mx + logf(s));
        }
        __syncthreads();
        // v update: v[n] = NORM_C - lse_m(Z[m][n] + u[m])
#pragma unroll
        for (int j = 0; j < 4; ++j) {
            int n = tid + j * 1024;
            float z[32];
#pragma unroll
            for (int i = 0; i < 32; ++i) z[i] = Zb[(size_t)i * HW_SZ + n] + u_s[i];
            float mx = z[0];
#pragma unroll
            for (int i = 1; i < 32; ++i) mx = fmaxf(mx, z[i]);
            float s = 0.f;
#pragma unroll
            for (int i = 0; i < 32; ++i) s += __expf(z[i] - mx);
            v_s[n] = NORM_C - (mx + logf(s));
        }
        __syncthreads();
    }
    if (tid < 32) u_g[b * M_CL + tid] = u_s[tid];
#pragma unroll
    for (int j = 0; j < 4; ++j)
        v_g[b * HW_SZ + tid + j * 1024] = v_s[tid + j * 1024];
}

// ---------------------------------------------------------------------------
// K6: v_tilde partials. Block: batch b, 256-n chunk, all 256 d x 32 m.
// thread: 4 consecutive d (dg), 8 m (mg). weights tile staged per 64 n.
// ---------------------------------------------------------------------------
__global__ __launch_bounds__(256) void vtilde_part(const float* __restrict__ xp,
                                                   const float* __restrict__ inv_norm,
                                                   const float* __restrict__ Z,
                                                   const float* __restrict__ u_g,
                                                   const float* __restrict__ v_g,
                                                   float* __restrict__ part) {
    __shared__ float wt[64][36];   // [n_local][m], pre-scaled by inv_norm
    __shared__ float u_l[32];
    const int tid = threadIdx.x;
    const int b = blockIdx.y, chunk = blockIdx.x;
    const int n0 = chunk * 256;
    const int dg = tid & 63, mg = tid >> 6;
    if (tid < 32) u_l[tid] = u_g[b * M_CL + tid];
    float4 acc[8];
#pragma unroll
    for (int j = 0; j < 8; ++j) acc[j] = make_float4(0.f, 0.f, 0.f, 0.f);
    const float* Zb  = Z + (size_t)b * M_CL * HW_SZ;
    const float* vb  = v_g + b * HW_SZ;
    const float* ivb = inv_norm + b * HW_SZ;
    __syncthreads();

    for (int t = 0; t < 4; ++t) {
        int nb = n0 + t * 64;
#pragma unroll
        for (int i = 0; i < 8; ++i) {   // 32 m x 64 n = 2048 elems
            int e = tid + i * 256;
            int m = e >> 6, nn = e & 63;
            float z = Zb[(size_t)m * HW_SZ + nb + nn];
            wt[nn][m] = __expf(z + u_l[m] + vb[nb + nn] - NORM_C) * ivb[nb + nn];
        }
        __syncthreads();
        const float* xpb = xp + ((size_t)b * HW_SZ + nb) * D_OUT;
#pragma unroll 4
        for (int nn = 0; nn < 64; ++nn) {
            float4 xv = *(const float4*)(xpb + (size_t)nn * D_OUT + dg * 4);
            float4 wa = *(const float4*)&wt[nn][mg * 8];
            float4 wb = *(const float4*)&wt[nn][mg * 8 + 4];
            float w[8] = {wa.x, wa.y, wa.z, wa.w, wb.x, wb.y, wb.z, wb.w};
#pragma unroll
            for (int j = 0; j < 8; ++j) {
                acc[j].x += w[j] * xv.x;
                acc[j].y += w[j] * xv.y;
                acc[j].z += w[j] * xv.z;
                acc[j].w += w[j] * xv.w;
            }
        }
        __syncthreads();
    }
#pragma unroll
    for (int j = 0; j < 8; ++j) {
        int m = mg * 8 + j;
        *(float4*)(part + (((size_t)b * 16 + chunk) * M_CL + m) * D_OUT + dg * 4) = acc[j];
    }
}

// ---------------------------------------------------------------------------
// K7: reduce 16 chunk-partials -> v_tilde
// ---------------------------------------------------------------------------
__global__ __launch_bounds__(256) void vtilde_reduce(const float* __restrict__ part,
                                                     float* __restrict__ out_vt) {
    int o = blockIdx.x * 256 + threadIdx.x;
    int b = o >> 13, r = o & 8191;
    float s = 0.f;
#pragma unroll
    for (int c = 0; c < 16; ++c)
        s += part[((size_t)(b * 16 + c)) * 8192 + r];
    out_vt[o] = s;
}

// ---------------------------------------------------------------------------
extern "C" void kernel_launch(void* const* d_in, const int* in_sizes, int n_in,
                              void* d_out, int out_size, void* d_ws, size_t ws_size,
                              hipStream_t stream) {
    const float* x      = (const float*)d_in[0];
    const float* conv_w = (const float*)d_in[1];
    const float* conv_b = (const float*)d_in[2];
    const float* v_in   = (const float*)d_in[3];

    float* out_vt = (float*)d_out;                 // [16][32][256]
    float* out_xp = (float*)d_out + 131072;        // [16][4096][256]

    float* ws       = (float*)d_ws;
    float* inv_norm = ws;                          // 65536
    float* w_n      = ws + 65536;                  // 8192
    float* Zbuf     = ws + 73728;                  // 2097152
    float* u_g      = ws + 2170880;                // 512
    float* v_g      = ws + 2171392;                // 65536
    float* part     = ws + 2236928;                // 2097152

    conv_gemm<<<dim3(32, 2, 16), 256, 0, stream>>>(x, conv_w, conv_b, out_xp);
    row_norms<<<16384, 256, 0, stream>>>(out_xp, inv_norm);
    w_norm<<<32, 64, 0, stream>>>(v_in, w_n);
    scores_k<<<dim3(32, 16), 256, 0, stream>>>(out_xp, inv_norm, w_n, Zbuf);
    sinkhorn_k<<<16, 1024, 0, stream>>>(Zbuf, u_g, v_g);
    vtilde_part<<<dim3(16, 16), 256, 0, stream>>>(out_xp, inv_norm, Zbuf, u_g, v_g, part);
    vtilde_reduce<<<512, 256, 0, stream>>>(part, out_vt);
}

// Round 2
// 382.460 us; speedup vs baseline: 1.9156x; 1.9156x over previous
//
#include <hip/hip_runtime.h>
#include <math.h>

#define NORM_C (-8.3255483f)   /* -log(32+4096) */

typedef __attribute__((ext_vector_type(8))) short bf16x8;
typedef __attribute__((ext_vector_type(4))) float f32x4;

union U8 { uint4 q; unsigned u[4]; bf16x8 v; };

__device__ inline unsigned short f2bf_rne(float f) {
    unsigned u = __float_as_uint(f);
    unsigned r = u + 0x7fffu + ((u >> 16) & 1u);
    return (unsigned short)(r >> 16);
}
// pack two floats -> (bf16(hi)<<16)|bf16(lo), round-half-up
__device__ inline unsigned pack_bf2(float lo, float hi) {
    unsigned a = __float_as_uint(lo) + 0x8000u;
    unsigned b = __float_as_uint(hi) + 0x8000u;
    return __builtin_amdgcn_perm(b, a, 0x07060302u);
}

// ---------------------------------------------------------------------------
// K0: convert conv_w [256][768] fp32 -> bf16 (RNE), same layout
// ---------------------------------------------------------------------------
__global__ __launch_bounds__(256) void w_cvt(const float* __restrict__ W,
                                             unsigned short* __restrict__ Wb) {
    int i = (blockIdx.x * 256 + threadIdx.x) * 4;
    float4 w = *(const float4*)(W + i);
    unsigned lo = (unsigned)f2bf_rne(w.x) | ((unsigned)f2bf_rne(w.y) << 16);
    unsigned hi = (unsigned)f2bf_rne(w.z) | ((unsigned)f2bf_rne(w.w) << 16);
    *(uint2*)(Wb + i) = make_uint2(lo, hi);
}

// ---------------------------------------------------------------------------
// K1: normalize clusters v[32][256] -> bf16 w_n
// ---------------------------------------------------------------------------
__global__ __launch_bounds__(64) void w_norm(const float* __restrict__ v_in,
                                             unsigned short* __restrict__ wnb) {
    const int lane = threadIdx.x;
    const int row = blockIdx.x;
    float4 v = *(const float4*)(v_in + row * 256 + lane * 4);
    float s = v.x * v.x + v.y * v.y + v.z * v.z + v.w * v.w;
#pragma unroll
    for (int off = 32; off > 0; off >>= 1) s += __shfl_xor(s, off);
    float inv = 1.0f / fmaxf(sqrtf(s), 1e-12f);
    unsigned lo = (unsigned)f2bf_rne(v.x * inv) | ((unsigned)f2bf_rne(v.y * inv) << 16);
    unsigned hi = (unsigned)f2bf_rne(v.z * inv) | ((unsigned)f2bf_rne(v.w * inv) << 16);
    *(uint2*)(wnb + row * 256 + lane * 4) = make_uint2(lo, hi);
}

// ---------------------------------------------------------------------------
// K2: conv as bf16 MFMA GEMM. A = W[d][c] (bf16), B = x[c][n] -> LDS [n][k].
// Block: 128 n x 256 d, BK=32, 4 waves (2x2: wd x wn). Fused bias + inv_norm.
// A LDS stride 20 words (b128-aligned frag reads); B stride 17 words (b32 reads).
// ---------------------------------------------------------------------------
__global__ __launch_bounds__(256) void conv_mfma(const float* __restrict__ x,
                                                 const unsigned short* __restrict__ Wb,
                                                 const float* __restrict__ bias,
                                                 float* __restrict__ xp,
                                                 float* __restrict__ inv_norm) {
    __shared__ unsigned As[256 * 20];   // W tile 256d x 32k (bf16 pairs)
    __shared__ unsigned Bs[128 * 17];   // x tile 128n x 32k
    __shared__ float ssq_s[128];

    const int tid = threadIdx.x;
    const int lane = tid & 63;
    const int wid = tid >> 6;
    const int wn = wid & 1, wd = wid >> 1;
    const int b = blockIdx.y;
    const int n0 = blockIdx.x * 128;
    const int l15 = lane & 15, l4 = lane >> 4;
    const float* xb = x + (size_t)b * 768 * 4096;

    f32x4 acc[8][4];
#pragma unroll
    for (int i = 0; i < 8; ++i)
#pragma unroll
        for (int j = 0; j < 4; ++j) acc[i][j] = (f32x4){0.f, 0.f, 0.f, 0.f};

    for (int k0 = 0; k0 < 768; k0 += 32) {
        __syncthreads();
        // stage W (bf16 direct copy): 256d x 32k = 1024 uint4-groups
#pragma unroll
        for (int i = 0; i < 4; ++i) {
            int f = tid + i * 256;
            int dd = f >> 2, c8 = f & 3;
            uint4 w = *(const uint4*)(Wb + (size_t)dd * 768 + k0 + c8 * 8);
            *(uint4*)&As[dd * 20 + c8 * 4] = w;
        }
        // stage x with transpose+cvt: 32c x 128n
#pragma unroll
        for (int i = 0; i < 4; ++i) {
            int f = tid + i * 256;
            int n2 = f & 63, ch = f >> 6;
            const float* p = xb + (size_t)(k0 + 2 * ch) * 4096 + n0 + 2 * n2;
            float2 g0 = *(const float2*)p;
            float2 g1 = *(const float2*)(p + 4096);
            Bs[(2 * n2) * 17 + ch] = pack_bf2(g0.x, g1.x);
            Bs[(2 * n2 + 1) * 17 + ch] = pack_bf2(g0.y, g1.y);
        }
        __syncthreads();

        U8 af[8];
#pragma unroll
        for (int dt = 0; dt < 8; ++dt) {
            int row = wd * 128 + dt * 16 + l15;
            af[dt].q = *(uint4*)&As[row * 20 + l4 * 4];
        }
#pragma unroll
        for (int nt = 0; nt < 4; ++nt) {
            int col = wn * 64 + nt * 16 + l15;
            int base = col * 17 + l4 * 4;
            U8 bf;
            bf.u[0] = Bs[base]; bf.u[1] = Bs[base + 1];
            bf.u[2] = Bs[base + 2]; bf.u[3] = Bs[base + 3];
#pragma unroll
            for (int dt = 0; dt < 8; ++dt)
                acc[dt][nt] = __builtin_amdgcn_mfma_f32_16x16x32_bf16(
                    af[dt].v, bf.v, acc[dt][nt], 0, 0, 0);
        }
    }

    // epilogue: bias, store xp, row sum-of-squares
    float ssq[4] = {0.f, 0.f, 0.f, 0.f};
#pragma unroll
    for (int dt = 0; dt < 8; ++dt) {
        int d = wd * 128 + dt * 16 + l4 * 4;
        float4 bi = *(const float4*)(bias + d);
#pragma unroll
        for (int nt = 0; nt < 4; ++nt) {
            int n = n0 + wn * 64 + nt * 16 + l15;
            float4 o = make_float4(acc[dt][nt].x + bi.x, acc[dt][nt].y + bi.y,
                                   acc[dt][nt].z + bi.z, acc[dt][nt].w + bi.w);
            *(float4*)(xp + ((size_t)(b * 4096 + n)) * 256 + d) = o;
            ssq[nt] += o.x * o.x + o.y * o.y + o.z * o.z + o.w * o.w;
        }
    }
#pragma unroll
    for (int nt = 0; nt < 4; ++nt) {
        ssq[nt] += __shfl_xor(ssq[nt], 16);
        ssq[nt] += __shfl_xor(ssq[nt], 32);
    }
    if (wd == 0 && l4 == 0) {
#pragma unroll
        for (int nt = 0; nt < 4; ++nt) ssq_s[wn * 64 + nt * 16 + l15] = ssq[nt];
    }
    __syncthreads();
    if (wd == 1 && l4 == 0) {
#pragma unroll
        for (int nt = 0; nt < 4; ++nt) {
            int nl = wn * 64 + nt * 16 + l15;
            float tot = ssq[nt] + ssq_s[nl];
            inv_norm[b * 4096 + n0 + nl] = 1.0f / fmaxf(sqrtf(tot), 1e-12f);
        }
    }
}

// ---------------------------------------------------------------------------
// K3: scores via MFMA, no LDS. A = xf (packed in-reg from fp32 xp * inv * 20),
// B = w bf16 (preloaded frags). Block: 4 waves x 16 n. Z[b][m][n] fp32.
// ---------------------------------------------------------------------------
__global__ __launch_bounds__(256) void scores_mfma(const float* __restrict__ xp,
                                                   const float* __restrict__ inv_norm,
                                                   const unsigned short* __restrict__ wnb,
                                                   float* __restrict__ Z) {
    const int tid = threadIdx.x;
    const int lane = tid & 63;
    const int wid = tid >> 6;
    const int l15 = lane & 15, l4 = lane >> 4;
    const int b = blockIdx.y, ng = blockIdx.x;
    const int n = ng * 64 + wid * 16 + l15;

    U8 wf[2][8];
#pragma unroll
    for (int mt = 0; mt < 2; ++mt)
#pragma unroll
        for (int s = 0; s < 8; ++s)
            wf[mt][s].q = *(const uint4*)(wnb + (mt * 16 + l15) * 256 + s * 32 + l4 * 8);

    const float invs = inv_norm[b * 4096 + n] * 20.0f;   // fold 1/EPS
    const float* xr = xp + ((size_t)(b * 4096 + n)) * 256 + l4 * 8;

    f32x4 acc0 = {0.f, 0.f, 0.f, 0.f}, acc1 = {0.f, 0.f, 0.f, 0.f};
#pragma unroll
    for (int s = 0; s < 8; ++s) {
        float4 p0 = *(const float4*)(xr + s * 32);
        float4 p1 = *(const float4*)(xr + s * 32 + 4);
        U8 af;
        af.u[0] = pack_bf2(p0.x * invs, p0.y * invs);
        af.u[1] = pack_bf2(p0.z * invs, p0.w * invs);
        af.u[2] = pack_bf2(p1.x * invs, p1.y * invs);
        af.u[3] = pack_bf2(p1.z * invs, p1.w * invs);
        acc0 = __builtin_amdgcn_mfma_f32_16x16x32_bf16(af.v, wf[0][s].v, acc0, 0, 0, 0);
        acc1 = __builtin_amdgcn_mfma_f32_16x16x32_bf16(af.v, wf[1][s].v, acc1, 0, 0, 0);
    }
    const int n_out = ng * 64 + wid * 16 + l4 * 4;
    *(f32x4*)&Z[((size_t)(b * 32 + l15)) * 4096 + n_out] = acc0;
    *(f32x4*)&Z[((size_t)(b * 32 + 16 + l15)) * 4096 + n_out] = acc1;
}

// ---------------------------------------------------------------------------
// K4: sinkhorn u-update: one block per (b,m); LSE over 4096 n.
// ---------------------------------------------------------------------------
template <int USE_V>
__global__ __launch_bounds__(256) void sink_u(const float* __restrict__ Z,
                                              const float* __restrict__ v_g,
                                              float* __restrict__ u_g) {
    __shared__ float wmx[4], wsum[4];
    const int tid = threadIdx.x;
    const int lane = tid & 63, wid = tid >> 6;
    const int b = blockIdx.x >> 5, m = blockIdx.x & 31;
    const float* zr = Z + ((size_t)(b * 32 + m)) * 4096;
    const float* vr = v_g + b * 4096;

    float z[16];
#pragma unroll
    for (int j = 0; j < 16; ++j) {
        int n = tid + j * 256;
        z[j] = USE_V ? (zr[n] + vr[n]) : zr[n];
    }
    float mx = z[0];
#pragma unroll
    for (int j = 1; j < 16; ++j) mx = fmaxf(mx, z[j]);
    float s = 0.f;
#pragma unroll
    for (int j = 0; j < 16; ++j) s += __expf(z[j] - mx);
#pragma unroll
    for (int off = 1; off < 64; off <<= 1) {
        float omx = __shfl_xor(mx, off);
        float os = __shfl_xor(s, off);
        float nm = fmaxf(mx, omx);
        s = s * __expf(mx - nm) + os * __expf(omx - nm);
        mx = nm;
    }
    if (lane == 0) { wmx[wid] = mx; wsum[wid] = s; }
    __syncthreads();
    if (tid == 0) {
        float gm = wmx[0], gs = wsum[0];
#pragma unroll
        for (int w = 1; w < 4; ++w) {
            float nm = fmaxf(gm, wmx[w]);
            gs = gs * __expf(gm - nm) + wsum[w] * __expf(wmx[w] - nm);
            gm = nm;
        }
        u_g[b * 32 + m] = NORM_C - (gm + __logf(gs));
    }
}

// ---------------------------------------------------------------------------
// K5: sinkhorn v-update: LSE over 32 m per column.
// ---------------------------------------------------------------------------
__global__ __launch_bounds__(512) void sink_v(const float* __restrict__ Z,
                                              const float* __restrict__ u_g,
                                              float* __restrict__ v_g) {
    __shared__ float u_s[32];
    const int tid = threadIdx.x;
    const int b = blockIdx.y;
    const int n = blockIdx.x * 512 + tid;
    if (tid < 32) u_s[tid] = u_g[b * 32 + tid];
    __syncthreads();
    float z[32];
#pragma unroll
    for (int m = 0; m < 32; ++m) z[m] = Z[((size_t)(b * 32 + m)) * 4096 + n] + u_s[m];
    float mx = z[0];
#pragma unroll
    for (int m = 1; m < 32; ++m) mx = fmaxf(mx, z[m]);
    float s = 0.f;
#pragma unroll
    for (int m = 0; m < 32; ++m) s += __expf(z[m] - mx);
    v_g[b * 4096 + n] = NORM_C - (mx + __logf(s));
}

// ---------------------------------------------------------------------------
// K6: v_tilde partials. v3 computed inline from u3. Block: (chunk of 256 n,
// d-half 128, b). Thread: 4 d x 4 m. Weights (incl inv_norm) staged per 64 n.
// ---------------------------------------------------------------------------
__global__ __launch_bounds__(256) void vtilde_part_k(const float* __restrict__ xp,
                                                     const float* __restrict__ inv_norm,
                                                     const float* __restrict__ Z,
                                                     const float* __restrict__ u_g,
                                                     float* __restrict__ part) {
    __shared__ float u_s[32];
    __shared__ float v3_s[256];
    __shared__ float inv_s[256];
    __shared__ float wt[64 * 36];
    const int tid = threadIdx.x;
    const int cx = blockIdx.x;
    const int chunk = cx >> 1, dh = cx & 1;
    const int b = blockIdx.y;
    const int n0 = chunk * 256;
    if (tid < 32) u_s[tid] = u_g[b * 32 + tid];
    __syncthreads();
    {   // v3 for this chunk + inv_norm stage
        int n = n0 + tid;
        float z[32];
#pragma unroll
        for (int m = 0; m < 32; ++m)
            z[m] = Z[((size_t)(b * 32 + m)) * 4096 + n] + u_s[m];
        float mx = z[0];
#pragma unroll
        for (int m = 1; m < 32; ++m) mx = fmaxf(mx, z[m]);
        float s = 0.f;
#pragma unroll
        for (int m = 0; m < 32; ++m) s += __expf(z[m] - mx);
        v3_s[tid] = NORM_C - (mx + __logf(s));
        inv_s[tid] = inv_norm[b * 4096 + n];
    }
    __syncthreads();

    const int dg = tid & 31, mq = tid >> 5;
    f32x4 acc[4];
#pragma unroll
    for (int j = 0; j < 4; ++j) acc[j] = (f32x4){0.f, 0.f, 0.f, 0.f};
    const float* xpb = xp + ((size_t)(b * 4096 + n0)) * 256 + dh * 128 + dg * 4;

    for (int t = 0; t < 4; ++t) {
#pragma unroll
        for (int i = 0; i < 8; ++i) {
            int e = tid + i * 256;
            int mW = e >> 6, nn = e & 63;
            int nl = t * 64 + nn;
            wt[nn * 36 + mW] =
                __expf(Z[((size_t)(b * 32 + mW)) * 4096 + n0 + nl] + u_s[mW] +
                       v3_s[nl] - NORM_C) * inv_s[nl];
        }
        __syncthreads();
#pragma unroll 4
        for (int nn = 0; nn < 64; ++nn) {
            float4 xv = *(const float4*)(xpb + (size_t)(t * 64 + nn) * 256);
            float4 wv = *(const float4*)&wt[nn * 36 + mq * 4];
            acc[0].x += wv.x * xv.x; acc[0].y += wv.x * xv.y; acc[0].z += wv.x * xv.z; acc[0].w += wv.x * xv.w;
            acc[1].x += wv.y * xv.x; acc[1].y += wv.y * xv.y; acc[1].z += wv.y * xv.z; acc[1].w += wv.y * xv.w;
            acc[2].x += wv.z * xv.x; acc[2].y += wv.z * xv.y; acc[2].z += wv.z * xv.z; acc[2].w += wv.z * xv.w;
            acc[3].x += wv.w * xv.x; acc[3].y += wv.w * xv.y; acc[3].z += wv.w * xv.z; acc[3].w += wv.w * xv.w;
        }
        __syncthreads();
    }
#pragma unroll
    for (int j = 0; j < 4; ++j) {
        int m = mq * 4 + j;
        *(f32x4*)&part[((size_t)(b * 16 + chunk)) * 8192 + m * 256 + dh * 128 + dg * 4] = acc[j];
    }
}

// ---------------------------------------------------------------------------
// K7: reduce 16 chunk-partials -> v_tilde
// ---------------------------------------------------------------------------
__global__ __launch_bounds__(256) void vtilde_reduce(const float* __restrict__ part,
                                                     float* __restrict__ out_vt) {
    int o = blockIdx.x * 256 + threadIdx.x;
    int b = o >> 13, r = o & 8191;
    float s = 0.f;
#pragma unroll
    for (int c = 0; c < 16; ++c)
        s += part[((size_t)(b * 16 + c)) * 8192 + r];
    out_vt[o] = s;
}

// ---------------------------------------------------------------------------
extern "C" void kernel_launch(void* const* d_in, const int* in_sizes, int n_in,
                              void* d_out, int out_size, void* d_ws, size_t ws_size,
                              hipStream_t stream) {
    const float* x      = (const float*)d_in[0];
    const float* conv_w = (const float*)d_in[1];
    const float* conv_b = (const float*)d_in[2];
    const float* v_in   = (const float*)d_in[3];

    float* out_vt = (float*)d_out;                 // [16][32][256]
    float* out_xp = (float*)d_out + 131072;        // [16][4096][256]

    float* ws = (float*)d_ws;
    float*          inv_norm = ws;                                  // 65536 fp32
    unsigned short* Wb       = (unsigned short*)(ws + 65536);       // 196608 bf16
    unsigned short* wnb      = (unsigned short*)(ws + 163840);      // 8192 bf16
    float*          Zbuf     = ws + 167936;                         // 2097152
    float*          u_g      = ws + 2265088;                        // 512
    float*          v_g      = ws + 2265600;                        // 65536
    float*          part     = ws + 2331136;                        // 2097152

    w_cvt<<<192, 256, 0, stream>>>(conv_w, Wb);
    w_norm<<<32, 64, 0, stream>>>(v_in, wnb);
    conv_mfma<<<dim3(32, 16), 256, 0, stream>>>(x, Wb, conv_b, out_xp, inv_norm);
    scores_mfma<<<dim3(64, 16), 256, 0, stream>>>(out_xp, inv_norm, wnb, Zbuf);
    sink_u<0><<<512, 256, 0, stream>>>(Zbuf, v_g, u_g);
    sink_v<<<dim3(8, 16), 512, 0, stream>>>(Zbuf, u_g, v_g);
    sink_u<1><<<512, 256, 0, stream>>>(Zbuf, v_g, u_g);
    sink_v<<<dim3(8, 16), 512, 0, stream>>>(Zbuf, u_g, v_g);
    sink_u<1><<<512, 256, 0, stream>>>(Zbuf, v_g, u_g);
    vtilde_part_k<<<dim3(32, 16), 256, 0, stream>>>(out_xp, inv_norm, Zbuf, u_g, part);
    vtilde_reduce<<<512, 256, 0, stream>>>(part, out_vt);
}

// Round 3
// 374.787 us; speedup vs baseline: 1.9548x; 1.0205x over previous
//
#include <hip/hip_runtime.h>
#include <math.h>

#define NORM_C (-8.3255483f)   /* -log(32+4096) */

typedef __attribute__((ext_vector_type(8))) short bf16x8;
typedef __attribute__((ext_vector_type(4))) float f32x4;

union U8 { uint4 q; unsigned u[4]; bf16x8 v; };

__device__ inline unsigned short f2bf_rne(float f) {
    unsigned u = __float_as_uint(f);
    unsigned r = u + 0x7fffu + ((u >> 16) & 1u);
    return (unsigned short)(r >> 16);
}
// pack two floats -> (bf16(hi)<<16)|bf16(lo)
__device__ inline unsigned pack_bf2(float lo, float hi) {
    unsigned a = __float_as_uint(lo) + 0x8000u;
    unsigned b = __float_as_uint(hi) + 0x8000u;
    return __builtin_amdgcn_perm(b, a, 0x07060302u);
}

// ---------------------------------------------------------------------------
// K0: fused prep. blocks 0..767: conv_w fp32->bf16. blocks 768..799: normalize
// clusters v[32][256] -> bf16.
// ---------------------------------------------------------------------------
__global__ __launch_bounds__(64) void w_prep(const float* __restrict__ W,
                                             const float* __restrict__ v_in,
                                             unsigned short* __restrict__ Wb,
                                             unsigned short* __restrict__ wnb) {
    const int bx = blockIdx.x, tid = threadIdx.x;
    if (bx < 768) {
        int i = (bx * 64 + tid) * 4;
        float4 w = *(const float4*)(W + i);
        unsigned lo = (unsigned)f2bf_rne(w.x) | ((unsigned)f2bf_rne(w.y) << 16);
        unsigned hi = (unsigned)f2bf_rne(w.z) | ((unsigned)f2bf_rne(w.w) << 16);
        *(uint2*)(Wb + i) = make_uint2(lo, hi);
    } else {
        int row = bx - 768;
        float4 v = *(const float4*)(v_in + row * 256 + tid * 4);
        float s = v.x * v.x + v.y * v.y + v.z * v.z + v.w * v.w;
#pragma unroll
        for (int off = 32; off > 0; off >>= 1) s += __shfl_xor(s, off);
        float inv = 1.0f / fmaxf(sqrtf(s), 1e-12f);
        unsigned lo = (unsigned)f2bf_rne(v.x * inv) | ((unsigned)f2bf_rne(v.y * inv) << 16);
        unsigned hi = (unsigned)f2bf_rne(v.z * inv) | ((unsigned)f2bf_rne(v.w * inv) << 16);
        *(uint2*)(wnb + row * 256 + tid * 4) = make_uint2(lo, hi);
    }
}

// ---------------------------------------------------------------------------
// K1: mega kernel. Phase 1: conv MFMA (W bf16 x x bf16 -> xp fp32 + inv_norm).
// Phase 2: scores MFMA (xf bf16 x w bf16 -> Z fp32) + u1 LSE partials.
// Block: 128 n x 256 d (full), 4 waves (wn x wd).
// ---------------------------------------------------------------------------
__global__ __launch_bounds__(256) void conv_mega(const float* __restrict__ x,
                                                 const unsigned short* __restrict__ Wb,
                                                 const float* __restrict__ bias,
                                                 const unsigned short* __restrict__ wnb,
                                                 float* __restrict__ xp,
                                                 float* __restrict__ inv_norm,
                                                 float* __restrict__ Z,
                                                 float2* __restrict__ u1p) {
    __shared__ unsigned As[256 * 20];    // W tile 256d x 32k
    __shared__ unsigned Bs[128 * 17];    // x tile 128n x 32k
    __shared__ float ssq_s[128];
    __shared__ float invs_s[128];
    __shared__ unsigned xfs[128 * 33];   // xf quarter: 128n x 64d (bf16 pairs)
    __shared__ float2 upart_s[4][32];

    const int tid = threadIdx.x;
    const int lane = tid & 63;
    const int wid = tid >> 6;
    const int wn = wid & 1, wd = wid >> 1;
    const int b = blockIdx.y;
    const int n0 = blockIdx.x * 128;
    const int l15 = lane & 15, l4 = lane >> 4;
    const float* xb = x + (size_t)b * 768 * 4096;

    f32x4 acc[8][4];
#pragma unroll
    for (int i = 0; i < 8; ++i)
#pragma unroll
        for (int j = 0; j < 4; ++j) acc[i][j] = (f32x4){0.f, 0.f, 0.f, 0.f};

    // ---------------- phase 1: conv ----------------
    for (int k0 = 0; k0 < 768; k0 += 32) {
        __syncthreads();
#pragma unroll
        for (int i = 0; i < 4; ++i) {
            int f = tid + i * 256;
            int dd = f >> 2, c8 = f & 3;
            uint4 w = *(const uint4*)(Wb + (size_t)dd * 768 + k0 + c8 * 8);
            *(uint4*)&As[dd * 20 + c8 * 4] = w;
        }
#pragma unroll
        for (int i = 0; i < 4; ++i) {
            int f = tid + i * 256;
            int n2 = f & 63, ch = f >> 6;
            const float* p = xb + (size_t)(k0 + 2 * ch) * 4096 + n0 + 2 * n2;
            float2 g0 = *(const float2*)p;
            float2 g1 = *(const float2*)(p + 4096);
            Bs[(2 * n2) * 17 + ch] = pack_bf2(g0.x, g1.x);
            Bs[(2 * n2 + 1) * 17 + ch] = pack_bf2(g0.y, g1.y);
        }
        __syncthreads();

        U8 af[8];
#pragma unroll
        for (int dt = 0; dt < 8; ++dt) {
            int row = wd * 128 + dt * 16 + l15;
            af[dt].q = *(uint4*)&As[row * 20 + l4 * 4];
        }
#pragma unroll
        for (int nt = 0; nt < 4; ++nt) {
            int col = wn * 64 + nt * 16 + l15;
            int base = col * 17 + l4 * 4;
            U8 bf;
            bf.u[0] = Bs[base]; bf.u[1] = Bs[base + 1];
            bf.u[2] = Bs[base + 2]; bf.u[3] = Bs[base + 3];
#pragma unroll
            for (int dt = 0; dt < 8; ++dt)
                acc[dt][nt] = __builtin_amdgcn_mfma_f32_16x16x32_bf16(
                    af[dt].v, bf.v, acc[dt][nt], 0, 0, 0);
        }
    }

    // epilogue: bias into acc, store xp, row sum-of-squares -> inv_norm
    float ssq[4] = {0.f, 0.f, 0.f, 0.f};
#pragma unroll
    for (int dt = 0; dt < 8; ++dt) {
        int d = wd * 128 + dt * 16 + l4 * 4;
        float4 bi = *(const float4*)(bias + d);
#pragma unroll
        for (int nt = 0; nt < 4; ++nt) {
            int n = n0 + wn * 64 + nt * 16 + l15;
            f32x4 o = acc[dt][nt];
            o.x += bi.x; o.y += bi.y; o.z += bi.z; o.w += bi.w;
            acc[dt][nt] = o;
            *(f32x4*)(xp + ((size_t)(b * 4096 + n)) * 256 + d) = o;
            ssq[nt] += o.x * o.x + o.y * o.y + o.z * o.z + o.w * o.w;
        }
    }
#pragma unroll
    for (int nt = 0; nt < 4; ++nt) {
        ssq[nt] += __shfl_xor(ssq[nt], 16);
        ssq[nt] += __shfl_xor(ssq[nt], 32);
    }
    if (wd == 0 && l4 == 0) {
#pragma unroll
        for (int nt = 0; nt < 4; ++nt) ssq_s[wn * 64 + nt * 16 + l15] = ssq[nt];
    }
    __syncthreads();
    if (wd == 1 && l4 == 0) {
#pragma unroll
        for (int nt = 0; nt < 4; ++nt) {
            int nl = wn * 64 + nt * 16 + l15;
            float inv = 1.0f / fmaxf(sqrtf(ssq[nt] + ssq_s[nl]), 1e-12f);
            invs_s[nl] = inv;
            inv_norm[b * 4096 + n0 + nl] = inv;
        }
    }

    // ---------------- phase 2: scores + u1 partials ----------------
    f32x4 accz[2][2];
#pragma unroll
    for (int i = 0; i < 2; ++i)
#pragma unroll
        for (int j = 0; j < 2; ++j) accz[i][j] = (f32x4){0.f, 0.f, 0.f, 0.f};

    for (int q = 0; q < 4; ++q) {
        __syncthreads();
        if (wd == (q >> 1)) {
#pragma unroll
            for (int dt4 = 0; dt4 < 4; ++dt4) {
                int dt = (q & 1) * 4 + dt4;
#pragma unroll
                for (int nt = 0; nt < 4; ++nt) {
                    int n = wn * 64 + nt * 16 + l15;
                    float inv = invs_s[n];
                    f32x4 a = acc[dt][nt];
                    int base = n * 33 + dt4 * 8 + l4 * 2;
                    xfs[base]     = pack_bf2(a.x * inv, a.y * inv);
                    xfs[base + 1] = pack_bf2(a.z * inv, a.w * inv);
                }
            }
        }
        __syncthreads();
#pragma unroll
        for (int s = 0; s < 2; ++s) {
            U8 wf[2];
#pragma unroll
            for (int mt = 0; mt < 2; ++mt)
                wf[mt].q = *(const uint4*)(wnb + (mt * 16 + l15) * 256 +
                                           q * 64 + s * 32 + l4 * 8);
#pragma unroll
            for (int sti = 0; sti < 2; ++sti) {
                int st = wid + sti * 4;
                int arow = (st * 16 + l15) * 33 + s * 16 + l4 * 4;
                U8 af;
                af.u[0] = xfs[arow]; af.u[1] = xfs[arow + 1];
                af.u[2] = xfs[arow + 2]; af.u[3] = xfs[arow + 3];
#pragma unroll
                for (int mt = 0; mt < 2; ++mt)
                    accz[sti][mt] = __builtin_amdgcn_mfma_f32_16x16x32_bf16(
                        af.v, wf[mt].v, accz[sti][mt], 0, 0, 0);
            }
        }
    }
    // scale by 1/EPS, write Z, emit u1 partials
#pragma unroll
    for (int sti = 0; sti < 2; ++sti)
#pragma unroll
        for (int mt = 0; mt < 2; ++mt) {
            accz[sti][mt].x *= 20.f; accz[sti][mt].y *= 20.f;
            accz[sti][mt].z *= 20.f; accz[sti][mt].w *= 20.f;
            int m = mt * 16 + l15;
            int st = wid + sti * 4;
            *(f32x4*)&Z[((size_t)(b * 32 + m)) * 4096 + n0 + st * 16 + l4 * 4] =
                accz[sti][mt];
        }
#pragma unroll
    for (int mt = 0; mt < 2; ++mt) {
        float v0[8] = {accz[0][mt].x, accz[0][mt].y, accz[0][mt].z, accz[0][mt].w,
                       accz[1][mt].x, accz[1][mt].y, accz[1][mt].z, accz[1][mt].w};
        float mx = v0[0];
#pragma unroll
        for (int i = 1; i < 8; ++i) mx = fmaxf(mx, v0[i]);
        float s = 0.f;
#pragma unroll
        for (int i = 0; i < 8; ++i) s += __expf(v0[i] - mx);
#pragma unroll
        for (int off = 16; off < 64; off <<= 1) {
            float omx = __shfl_xor(mx, off);
            float os = __shfl_xor(s, off);
            float nm = fmaxf(mx, omx);
            s = s * __expf(mx - nm) + os * __expf(omx - nm);
            mx = nm;
        }
        if (lane < 16) upart_s[wid][mt * 16 + lane] = make_float2(mx, s);
    }
    __syncthreads();
    if (wid == 0 && lane < 32) {
        float2 p = upart_s[0][lane];
        float mx = p.x, s = p.y;
#pragma unroll
        for (int w = 1; w < 4; ++w) {
            float2 qq = upart_s[w][lane];
            float nm = fmaxf(mx, qq.x);
            s = s * __expf(mx - nm) + qq.y * __expf(qq.x - nm);
            mx = nm;
        }
        u1p[((size_t)b * 32 + blockIdx.x) * 32 + lane] = make_float2(mx, s);
    }
}

// ---------------------------------------------------------------------------
// K2: sinkhorn v-update. FIRST=1: derive u from u1 partials; else from u_g.
// ---------------------------------------------------------------------------
template <int FIRST>
__global__ __launch_bounds__(512) void sink_v(const float* __restrict__ Z,
                                              const float2* __restrict__ u1p,
                                              const float* __restrict__ u_g,
                                              float* __restrict__ v_g) {
    __shared__ float u_s[32];
    const int tid = threadIdx.x;
    const int b = blockIdx.y;
    const int n = blockIdx.x * 512 + tid;
    if (tid < 32) {
        if (FIRST) {
            float2 p = u1p[((size_t)b * 32) * 32 + tid];
            float mx = p.x, s = p.y;
#pragma unroll 4
            for (int t = 1; t < 32; ++t) {
                float2 q = u1p[((size_t)b * 32 + t) * 32 + tid];
                float nm = fmaxf(mx, q.x);
                s = s * __expf(mx - nm) + q.y * __expf(q.x - nm);
                mx = nm;
            }
            u_s[tid] = NORM_C - (mx + __logf(s));
        } else {
            u_s[tid] = u_g[b * 32 + tid];
        }
    }
    __syncthreads();
    float z[32];
#pragma unroll
    for (int m = 0; m < 32; ++m) z[m] = Z[((size_t)(b * 32 + m)) * 4096 + n] + u_s[m];
    float mx = z[0];
#pragma unroll
    for (int m = 1; m < 32; ++m) mx = fmaxf(mx, z[m]);
    float s = 0.f;
#pragma unroll
    for (int m = 0; m < 32; ++m) s += __expf(z[m] - mx);
    v_g[b * 4096 + n] = NORM_C - (mx + __logf(s));
}

// ---------------------------------------------------------------------------
// K3: sinkhorn u-update: one block per (b,m); LSE over 4096 n of Z+v.
// ---------------------------------------------------------------------------
__global__ __launch_bounds__(256) void sink_u(const float* __restrict__ Z,
                                              const float* __restrict__ v_g,
                                              float* __restrict__ u_g) {
    __shared__ float wmx[4], wsum[4];
    const int tid = threadIdx.x;
    const int lane = tid & 63, wid = tid >> 6;
    const int b = blockIdx.x >> 5, m = blockIdx.x & 31;
    const float* zr = Z + ((size_t)(b * 32 + m)) * 4096;
    const float* vr = v_g + b * 4096;

    float z[16];
#pragma unroll
    for (int j = 0; j < 16; ++j) {
        int n = tid + j * 256;
        z[j] = zr[n] + vr[n];
    }
    float mx = z[0];
#pragma unroll
    for (int j = 1; j < 16; ++j) mx = fmaxf(mx, z[j]);
    float s = 0.f;
#pragma unroll
    for (int j = 0; j < 16; ++j) s += __expf(z[j] - mx);
#pragma unroll
    for (int off = 1; off < 64; off <<= 1) {
        float omx = __shfl_xor(mx, off);
        float os = __shfl_xor(s, off);
        float nm = fmaxf(mx, omx);
        s = s * __expf(mx - nm) + os * __expf(omx - nm);
        mx = nm;
    }
    if (lane == 0) { wmx[wid] = mx; wsum[wid] = s; }
    __syncthreads();
    if (tid == 0) {
        float gm = wmx[0], gs = wsum[0];
#pragma unroll
        for (int w = 1; w < 4; ++w) {
            float nm = fmaxf(gm, wmx[w]);
            gs = gs * __expf(gm - nm) + wsum[w] * __expf(wmx[w] - nm);
            gm = nm;
        }
        u_g[b * 32 + m] = NORM_C - (gm + __logf(gs));
    }
}

// ---------------------------------------------------------------------------
// K4: v_tilde partials. v3 computed inline from u3 (= u_g). Block: (chunk of
// 256 n x d-half 128, b). Thread: 4 d x 4 m.
// ---------------------------------------------------------------------------
__global__ __launch_bounds__(256) void vtilde_part_k(const float* __restrict__ xp,
                                                     const float* __restrict__ inv_norm,
                                                     const float* __restrict__ Z,
                                                     const float* __restrict__ u_g,
                                                     float* __restrict__ part) {
    __shared__ float u_s[32];
    __shared__ float v3_s[256];
    __shared__ float inv_s[256];
    __shared__ float wt[64 * 36];
    const int tid = threadIdx.x;
    const int cx = blockIdx.x;
    const int chunk = cx >> 1, dh = cx & 1;
    const int b = blockIdx.y;
    const int n0 = chunk * 256;
    if (tid < 32) u_s[tid] = u_g[b * 32 + tid];
    __syncthreads();
    {
        int n = n0 + tid;
        float z[32];
#pragma unroll
        for (int m = 0; m < 32; ++m)
            z[m] = Z[((size_t)(b * 32 + m)) * 4096 + n] + u_s[m];
        float mx = z[0];
#pragma unroll
        for (int m = 1; m < 32; ++m) mx = fmaxf(mx, z[m]);
        float s = 0.f;
#pragma unroll
        for (int m = 0; m < 32; ++m) s += __expf(z[m] - mx);
        v3_s[tid] = NORM_C - (mx + __logf(s));
        inv_s[tid] = inv_norm[b * 4096 + n];
    }
    __syncthreads();

    const int dg = tid & 31, mq = tid >> 5;
    f32x4 acc[4];
#pragma unroll
    for (int j = 0; j < 4; ++j) acc[j] = (f32x4){0.f, 0.f, 0.f, 0.f};
    const float* xpb = xp + ((size_t)(b * 4096 + n0)) * 256 + dh * 128 + dg * 4;

    for (int t = 0; t < 4; ++t) {
#pragma unroll
        for (int i = 0; i < 8; ++i) {
            int e = tid + i * 256;
            int mW = e >> 6, nn = e & 63;
            int nl = t * 64 + nn;
            wt[nn * 36 + mW] =
                __expf(Z[((size_t)(b * 32 + mW)) * 4096 + n0 + nl] + u_s[mW] +
                       v3_s[nl] - NORM_C) * inv_s[nl];
        }
        __syncthreads();
#pragma unroll 4
        for (int nn = 0; nn < 64; ++nn) {
            float4 xv = *(const float4*)(xpb + (size_t)(t * 64 + nn) * 256);
            float4 wv = *(const float4*)&wt[nn * 36 + mq * 4];
            acc[0].x += wv.x * xv.x; acc[0].y += wv.x * xv.y; acc[0].z += wv.x * xv.z; acc[0].w += wv.x * xv.w;
            acc[1].x += wv.y * xv.x; acc[1].y += wv.y * xv.y; acc[1].z += wv.y * xv.z; acc[1].w += wv.y * xv.w;
            acc[2].x += wv.z * xv.x; acc[2].y += wv.z * xv.y; acc[2].z += wv.z * xv.z; acc[2].w += wv.z * xv.w;
            acc[3].x += wv.w * xv.x; acc[3].y += wv.w * xv.y; acc[3].z += wv.w * xv.z; acc[3].w += wv.w * xv.w;
        }
        __syncthreads();
    }
#pragma unroll
    for (int j = 0; j < 4; ++j) {
        int m = mq * 4 + j;
        *(f32x4*)&part[((size_t)(b * 16 + chunk)) * 8192 + m * 256 + dh * 128 + dg * 4] = acc[j];
    }
}

// ---------------------------------------------------------------------------
// K5: reduce 16 chunk-partials -> v_tilde
// ---------------------------------------------------------------------------
__global__ __launch_bounds__(256) void vtilde_reduce(const float* __restrict__ part,
                                                     float* __restrict__ out_vt) {
    int o = blockIdx.x * 256 + threadIdx.x;
    int b = o >> 13, r = o & 8191;
    float s = 0.f;
#pragma unroll
    for (int c = 0; c < 16; ++c)
        s += part[((size_t)(b * 16 + c)) * 8192 + r];
    out_vt[o] = s;
}

// ---------------------------------------------------------------------------
extern "C" void kernel_launch(void* const* d_in, const int* in_sizes, int n_in,
                              void* d_out, int out_size, void* d_ws, size_t ws_size,
                              hipStream_t stream) {
    const float* x      = (const float*)d_in[0];
    const float* conv_w = (const float*)d_in[1];
    const float* conv_b = (const float*)d_in[2];
    const float* v_in   = (const float*)d_in[3];

    float* out_vt = (float*)d_out;                 // [16][32][256]
    float* out_xp = (float*)d_out + 131072;        // [16][4096][256]

    float* ws = (float*)d_ws;
    float*          inv_norm = ws;                                  // 65536
    unsigned short* Wb       = (unsigned short*)(ws + 65536);       // 196608 bf16
    unsigned short* wnb      = (unsigned short*)(ws + 163840);      // 8192 bf16
    float*          Zbuf     = ws + 167936;                         // 2097152
    float2*         u1p      = (float2*)(ws + 2265088);             // 16384 float2
    float*          u_g      = ws + 2297856;                        // 512
    float*          v_g      = ws + 2298368;                        // 65536
    float*          part     = ws + 2363904;                        // 2097152

    w_prep<<<800, 64, 0, stream>>>(conv_w, v_in, Wb, wnb);
    conv_mega<<<dim3(32, 16), 256, 0, stream>>>(x, Wb, conv_b, wnb, out_xp,
                                                inv_norm, Zbuf, u1p);
    sink_v<1><<<dim3(8, 16), 512, 0, stream>>>(Zbuf, u1p, u_g, v_g);   // v1 (u1 from partials)
    sink_u<<<512, 256, 0, stream>>>(Zbuf, v_g, u_g);                   // u2
    sink_v<0><<<dim3(8, 16), 512, 0, stream>>>(Zbuf, u1p, u_g, v_g);   // v2
    sink_u<<<512, 256, 0, stream>>>(Zbuf, v_g, u_g);                   // u3
    vtilde_part_k<<<dim3(32, 16), 256, 0, stream>>>(out_xp, inv_norm, Zbuf, u_g, part);
    vtilde_reduce<<<512, 256, 0, stream>>>(part, out_vt);
}